// Round 8
// baseline (29281.805 us; speedup 1.0000x reference)
//
#include <hip/hip_runtime.h>
#include <math.h>

#define B_ 32
#define T_ 1024
#define M_ 40

// ---------------- weight prep (transposes for coalesced access) ----------------
__global__ void prep_kernel(const float* __restrict__ W_hh, const float* __restrict__ W2,
                            const float* __restrict__ W3, const float* __restrict__ W_ih,
                            float* __restrict__ WhhT, float* __restrict__ W2t,
                            float* __restrict__ W3t, float* __restrict__ WihT4) {
  int idx = blockIdx.x * 256 + threadIdx.x;
  if (idx < 196608) {  // WhhT[k][j] = W_hh[j][k]
    int k = idx / 768, j = idx % 768;
    WhhT[idx] = W_hh[j * 256 + k];
    return;
  }
  idx -= 196608;
  if (idx < 147456) {  // W2t[tap][ci][co]
    int tap = idx >> 14, ci = (idx >> 7) & 127, co = idx & 127;
    W2t[idx] = W2[(co * 128 + ci) * 9 + tap];
    return;
  }
  idx -= 147456;
  if (idx < 147456) {  // W3t[tap][ci][co]
    int tap = idx >> 14, ci = (idx >> 7) & 127, co = idx & 127;
    W3t[idx] = W3[(co * 128 + ci) * 9 + tap];
    return;
  }
  idx -= 147456;
  if (idx < 98304) {  // WihT4[k/4][j][k%4] = W_ih[j][k] (x-part, k<128)
    int khi = idx / 3072, rem = idx % 3072, j = rem >> 2, klo = rem & 3;
    WihT4[idx] = W_ih[j * 138 + khi * 4 + klo];
  }
}

// prep2: repack STREAMED W_hh cols for the 256-thread rnn (R15 partition).
// Streamed k-cols (172 of 256): k=48..127 (sb 0..19), k=164..255 (sb 20..42).
// Layout: Wstr[(sb*3+p)*1024 + d*4 + u] = W_hh[(p*256+d)*256 + kb+u]
// so thread d reads one float4 (4 consecutive k) per (sb, plane) — 16B/lane coalesced.
__global__ void prep2_kernel(const float* __restrict__ W_hh, float* __restrict__ Wstr) {
  int idx = blockIdx.x * 256 + threadIdx.x;
  if (idx >= 132096) return;  // 43 sb * 3 p * 1024
  int sb = idx / 3072, rem = idx % 3072;
  int p = rem / 1024, r2 = rem % 1024;
  int d = r2 >> 2, u = r2 & 3;
  int kb = (sb < 20) ? (48 + sb * 4) : (164 + (sb - 20) * 4);
  Wstr[idx] = W_hh[(p * 256 + d) * 256 + kb + u];
}

// ---------------- fused conv1+pool5 + conv2+pool4 ----------------
// grid (T/4, B), block 256.  y2: [B][T][2][128]
__global__ __launch_bounds__(256) void conv12_kernel(
    const float* __restrict__ x, const float* __restrict__ W1, const float* __restrict__ b1,
    const float* __restrict__ W2t, const float* __restrict__ b2, float* __restrict__ y2) {
  __shared__ float xt[8 * 42];          // x rows t0-2..t0+5, mel slots -1..40
  __shared__ float y1s[6 * 128 * 12];   // y1 rows t0-1..t0+4, [row][c][mslot 0..9 (=-1..8), pad]
  const int tid = threadIdx.x;
  const int t0 = blockIdx.x * 4;
  const int b = blockIdx.y;
  for (int idx = tid; idx < 8 * 42; idx += 256) {
    int row = idx / 42, slot = idx % 42;
    int t_in = t0 - 2 + row, m = slot - 1;
    float v = 0.f;
    if (t_in >= 0 && t_in < T_ && m >= 0 && m < M_) v = x[(b * T_ + t_in) * M_ + m];
    xt[idx] = v;
  }
  __syncthreads();
  const int c = tid & 127, q = tid >> 7;
  float w1[9];
#pragma unroll
  for (int i = 0; i < 9; ++i) w1[i] = W1[c * 9 + i];
  const float b1c = b1[c];
  for (int rr = 0; rr < 3; ++rr) {
    const int r = q * 3 + rr;
    const int t_in = t0 - 1 + r;
    float* yrow = &y1s[(r * 128 + c) * 12];
    if (t_in < 0 || t_in >= T_) {
#pragma unroll
      for (int s = 0; s < 12; ++s) yrow[s] = 0.f;
    } else {
      yrow[0] = 0.f; yrow[9] = 0.f; yrow[10] = 0.f; yrow[11] = 0.f;
#pragma unroll
      for (int mo = 0; mo < 8; ++mo) {
        float mx = -1e30f;
#pragma unroll
        for (int i5 = 0; i5 < 5; ++i5) {
          const int mp = mo * 5 + i5;
          float s = b1c;
#pragma unroll
          for (int dt = 0; dt < 3; ++dt)
#pragma unroll
            for (int dm = 0; dm < 3; ++dm)
              s += xt[(r + dt) * 42 + mp + dm] * w1[dt * 3 + dm];
          mx = fmaxf(mx, s);
        }
        yrow[1 + mo] = fmaxf(mx, 0.f);  // relu after (pool of conv+b); relu monotone
      }
    }
  }
  __syncthreads();
  // conv2: thread (co, tq) computes 2 t x 8 m outputs
  const int co = c, tq = q;
  float acc[2][8];
#pragma unroll
  for (int tl = 0; tl < 2; ++tl)
#pragma unroll
    for (int mo = 0; mo < 8; ++mo) acc[tl][mo] = 0.f;
  for (int ci = 0; ci < 128; ++ci) {
    float w[9];
#pragma unroll
    for (int i = 0; i < 9; ++i) w[i] = W2t[i * 16384 + ci * 128 + co];
    float xv[4][10];
#pragma unroll
    for (int rr = 0; rr < 4; ++rr) {
      const float* p = &y1s[((2 * tq + rr) * 128 + ci) * 12];
      const float4 a = *(const float4*)p;
      const float4 bq = *(const float4*)(p + 4);
      const float2 cq = *(const float2*)(p + 8);
      xv[rr][0] = a.x; xv[rr][1] = a.y; xv[rr][2] = a.z; xv[rr][3] = a.w;
      xv[rr][4] = bq.x; xv[rr][5] = bq.y; xv[rr][6] = bq.z; xv[rr][7] = bq.w;
      xv[rr][8] = cq.x; xv[rr][9] = cq.y;
    }
#pragma unroll
    for (int dt = 0; dt < 3; ++dt)
#pragma unroll
      for (int dm = 0; dm < 3; ++dm) {
        const float wv = w[dt * 3 + dm];
#pragma unroll
        for (int tl = 0; tl < 2; ++tl)
#pragma unroll
          for (int mo = 0; mo < 8; ++mo)
            acc[tl][mo] += xv[tl + dt][mo + dm] * wv;
      }
  }
  const float b2c = b2[co];
#pragma unroll
  for (int tl = 0; tl < 2; ++tl) {
    const int t = t0 + 2 * tq + tl;
    float m0 = fmaxf(fmaxf(acc[tl][0], acc[tl][1]), fmaxf(acc[tl][2], acc[tl][3])) + b2c;
    float m1 = fmaxf(fmaxf(acc[tl][4], acc[tl][5]), fmaxf(acc[tl][6], acc[tl][7])) + b2c;
    y2[((b * T_ + t) * 2 + 0) * 128 + co] = fmaxf(m0, 0.f);
    y2[((b * T_ + t) * 2 + 1) * 128 + co] = fmaxf(m1, 0.f);
  }
}

// ---------------- conv3+pool2 -> feats [T][B][128] ----------------
__global__ __launch_bounds__(256) void conv3_kernel(
    const float* __restrict__ y2, const float* __restrict__ W3t, const float* __restrict__ b3,
    float* __restrict__ feats) {
  __shared__ float y2s[6 * 128 * 4];  // [row][ci][mslot 0..3 (=-1..2)]
  const int tid = threadIdx.x;
  const int t0 = blockIdx.x * 4;
  const int b = blockIdx.y;
  for (int idx = tid; idx < 768; idx += 256) {
    int row = idx / 128, ci = idx % 128;
    y2s[(row * 128 + ci) * 4 + 0] = 0.f;
    y2s[(row * 128 + ci) * 4 + 3] = 0.f;
  }
  for (int idx = tid; idx < 6 * 256; idx += 256) {
    int row = idx / 256, rem = idx % 256;
    int m = rem >> 7, ci = rem & 127;
    int t_in = t0 - 1 + row;
    float v = 0.f;
    if (t_in >= 0 && t_in < T_) v = y2[((b * T_ + t_in) * 2 + m) * 128 + ci];
    y2s[(row * 128 + ci) * 4 + 1 + m] = v;
  }
  __syncthreads();
  const int co = tid & 127, tq = tid >> 7;
  float acc[2][2] = {{0.f, 0.f}, {0.f, 0.f}};
  for (int ci = 0; ci < 128; ++ci) {
    float w[9];
#pragma unroll
    for (int i = 0; i < 9; ++i) w[i] = W3t[i * 16384 + ci * 128 + co];
    float4 xr[4];
#pragma unroll
    for (int rr = 0; rr < 4; ++rr)
      xr[rr] = *(const float4*)&y2s[((2 * tq + rr) * 128 + ci) * 4];
#pragma unroll
    for (int dt = 0; dt < 3; ++dt)
#pragma unroll
      for (int tl = 0; tl < 2; ++tl) {
        const float4 v = xr[tl + dt];
        acc[tl][0] += v.y * w[dt * 3 + 1] + v.z * w[dt * 3 + 2];  // m=0: taps dm=1,2
        acc[tl][1] += v.y * w[dt * 3 + 0] + v.z * w[dt * 3 + 1];  // m=1: taps dm=0,1
      }
  }
  const float b3c = b3[co];
#pragma unroll
  for (int tl = 0; tl < 2; ++tl) {
    const int t = t0 + 2 * tq + tl;
    float f = fmaxf(fmaxf(acc[tl][0], acc[tl][1]) + b3c, 0.f);
    feats[(t * B_ + b) * 128 + co] = f;
  }
}

// ---------------- gi_x = feats @ W_ih_x^T + b_ih -> [T*B][768] ----------------
__global__ __launch_bounds__(256) void gid_kernel(
    const float* __restrict__ feats, const float* __restrict__ WihT4,
    const float* __restrict__ b_ih, float* __restrict__ gi) {
  __shared__ float fs[32 * 128];
  const int tid = threadIdx.x;
  const int jb = blockIdx.x;  // 0..2
  const int rb = blockIdx.y;  // 0..1023
  const float4* src = (const float4*)(feats + rb * 32 * 128);
  float4* dst = (float4*)fs;
  for (int i = tid; i < 1024; i += 256) dst[i] = src[i];
  __syncthreads();
  const int j = jb * 256 + tid;
  float acc[32];
#pragma unroll
  for (int r = 0; r < 32; ++r) acc[r] = 0.f;
  for (int k4 = 0; k4 < 32; ++k4) {
    const float4 w4 = *(const float4*)&WihT4[(k4 * 768 + j) * 4];
#pragma unroll
    for (int r = 0; r < 32; ++r) {
      const float4 f4 = *(const float4*)&fs[r * 128 + k4 * 4];
      acc[r] += f4.x * w4.x + f4.y * w4.y + f4.z * w4.z + f4.w * w4.w;
    }
  }
  const float bj = b_ih[j];
  for (int r = 0; r < 32; ++r) gi[(rb * 32 + r) * 768 + j] = acc[r] + bj;
}

// ---------------- persistent GRU: 32 blocks x 256 threads (thread d owns dim d) ----------------
// R15 = R12/R4 structure (harness-verified fp order, absmax 0.001953125) with a
// pin that FITS the 256-VGPR arch cap.  Evidence matrix:
//  - wpe(1,1) @ 256thr is the ONLY regime where pins materialize (R4: VGPR=256,
//    chose spill over remat even when over budget -> materialization is sticky).
//  - R4's failure was purely overflow (336 pin + ~50 working > 256 -> scratch at
//    1-wave latency).  R6 (512thr, wpe(2,2), 144 pin) remat'd to 128.
// Budget here: pin k=0..47 x 3 planes = 144 VGPRs + ~55 working ~ 200 <= 256
// (slack ~56).  LDS keeps k=128..163 (36 cols, 110.6 KB).  Streamed: 172 cols
// (k=48..127, 164..255) = 516 KB/step vs R0's effective 672 KB (-23%).
// Accumulation order identical to R12: 4 slice accumulators (k 0..63 / 64..127 /
// 128..191 / 192..255), ascending-k 4-wide groups, gate sum bhh + s0+s1+s2+s3.
// Health checks: VGPR_Count in [180,240] and WRITE_SIZE ~2.4-3 MB.
// VGPR<=130 => remat returned; WRITE_SIZE>>10MB => spill.  Either => revert R0.
__global__ __attribute__((amdgpu_flat_work_group_size(256, 256), amdgpu_waves_per_eu(1, 1)))
void rnn_kernel(
    const float* __restrict__ gi, const float* __restrict__ WhhT,
    const float* __restrict__ Wstr, const float* __restrict__ W_ih,
    const float* __restrict__ b_hh, const float* __restrict__ Wf,
    const float* __restrict__ bf, const float* __restrict__ targets,
    const int* __restrict__ force_mask, float* __restrict__ out) {
  __shared__ float Wl2[36 * 768];          // k=128..163, [col][p*256+d]  110.6 KB
  __shared__ float wtf[10 * 768];          // 30 KB
  __shared__ float wfs[10 * 256];          // 10 KB
  __shared__ __align__(16) float h_s[256];
  __shared__ float tf_s[10];
  __shared__ float bf_s[10];
  const int tid = threadIdx.x;  // = hidden dim d
  const int b = blockIdx.x;
  // ---- stage LDS ----
  for (int idx = tid; idx < 36 * 768; idx += 256) {
    int col = idx / 768, j = idx % 768;
    Wl2[idx] = WhhT[(128 + col) * 768 + j];
  }
  for (int idx = tid; idx < 7680; idx += 256) {
    int cc = idx / 768, j = idx % 768;
    wtf[idx] = W_ih[j * 138 + 128 + cc];
  }
  for (int idx = tid; idx < 2560; idx += 256) wfs[idx] = Wf[idx];
  h_s[tid] = 0.f;
  if (tid < 10) { tf_s[tid] = 0.f; bf_s[tid] = bf[tid]; }
  const float bhh_r = b_hh[tid];
  const float bhh_z = b_hh[256 + tid];
  const float bhh_n = b_hh[512 + tid];
  // ---- VGPR pin k=0..47 for all 3 planes: 144 regs ----
  float wpA[48], wpB[48], wpC[48];
#pragma unroll
  for (int kk = 0; kk < 48; ++kk) {
    wpA[kk] = WhhT[kk * 768 + tid];
    wpB[kk] = WhhT[kk * 768 + 256 + tid];
    wpC[kk] = WhhT[kk * 768 + 512 + tid];
  }
  int fm_r = 0;
  float tg_r[10];
  if (tid == 0) {
    fm_r = force_mask[b];  // fm[0]
#pragma unroll
    for (int cc = 0; cc < 10; ++cc) tg_r[cc] = targets[(b * T_) * 10 + cc];
  }
  const float4* W4 = (const float4*)Wstr;
  __syncthreads();

  for (int t = 0; t < T_; ++t) {
    // ---- phase A: gi loads + matvec (thread-local partials) + out(t-1) on wave 0 ----
    const int gb = (t * B_ + b) * 768 + tid;
    const float gi_r = gi[gb], gi_z = gi[gb + 256], gi_n = gi[gb + 512];
    float a0[4], a1[4], a2[4];
#pragma unroll
    for (int s = 0; s < 4; ++s) { a0[s] = 0.f; a1[s] = 0.f; a2[s] = 0.f; }
    // slice 0, k=0..47: VGPR pin (12 groups)
#pragma unroll
    for (int g = 0; g < 12; ++g) {
      const float4 h4 = *(const float4*)&h_s[g * 4];
      a0[0] += wpA[g * 4 + 0] * h4.x + wpA[g * 4 + 1] * h4.y + wpA[g * 4 + 2] * h4.z + wpA[g * 4 + 3] * h4.w;
      a1[0] += wpB[g * 4 + 0] * h4.x + wpB[g * 4 + 1] * h4.y + wpB[g * 4 + 2] * h4.z + wpB[g * 4 + 3] * h4.w;
      a2[0] += wpC[g * 4 + 0] * h4.x + wpC[g * 4 + 1] * h4.y + wpC[g * 4 + 2] * h4.z + wpC[g * 4 + 3] * h4.w;
    }
    // slice 0, k=48..63: streamed (sb 0..3)
#pragma unroll
    for (int sb = 0; sb < 4; ++sb) {
      const float4 h4 = *(const float4*)&h_s[48 + sb * 4];
      const float4 w0 = W4[(sb * 3 + 0) * 256 + tid];
      const float4 w1 = W4[(sb * 3 + 1) * 256 + tid];
      const float4 w2 = W4[(sb * 3 + 2) * 256 + tid];
      a0[0] += w0.x * h4.x + w0.y * h4.y + w0.z * h4.z + w0.w * h4.w;
      a1[0] += w1.x * h4.x + w1.y * h4.y + w1.z * h4.z + w1.w * h4.w;
      a2[0] += w2.x * h4.x + w2.y * h4.y + w2.z * h4.z + w2.w * h4.w;
    }
    // slice 1, k=64..127: streamed (sb 4..19)
#pragma unroll
    for (int sb = 4; sb < 20; ++sb) {
      const float4 h4 = *(const float4*)&h_s[48 + sb * 4];
      const float4 w0 = W4[(sb * 3 + 0) * 256 + tid];
      const float4 w1 = W4[(sb * 3 + 1) * 256 + tid];
      const float4 w2 = W4[(sb * 3 + 2) * 256 + tid];
      a0[1] += w0.x * h4.x + w0.y * h4.y + w0.z * h4.z + w0.w * h4.w;
      a1[1] += w1.x * h4.x + w1.y * h4.y + w1.z * h4.z + w1.w * h4.w;
      a2[1] += w2.x * h4.x + w2.y * h4.y + w2.z * h4.z + w2.w * h4.w;
    }
    // slice 2, k=128..163: LDS (9 groups)
#pragma unroll
    for (int g = 0; g < 9; ++g) {
      const float4 h4 = *(const float4*)&h_s[128 + g * 4];
      const float wa0 = Wl2[(g * 4 + 0) * 768 + tid];
      const float wa1 = Wl2[(g * 4 + 1) * 768 + tid];
      const float wa2 = Wl2[(g * 4 + 2) * 768 + tid];
      const float wa3 = Wl2[(g * 4 + 3) * 768 + tid];
      const float wb0 = Wl2[(g * 4 + 0) * 768 + 256 + tid];
      const float wb1 = Wl2[(g * 4 + 1) * 768 + 256 + tid];
      const float wb2 = Wl2[(g * 4 + 2) * 768 + 256 + tid];
      const float wb3 = Wl2[(g * 4 + 3) * 768 + 256 + tid];
      const float wc0 = Wl2[(g * 4 + 0) * 768 + 512 + tid];
      const float wc1 = Wl2[(g * 4 + 1) * 768 + 512 + tid];
      const float wc2 = Wl2[(g * 4 + 2) * 768 + 512 + tid];
      const float wc3 = Wl2[(g * 4 + 3) * 768 + 512 + tid];
      a0[2] += wa0 * h4.x + wa1 * h4.y + wa2 * h4.z + wa3 * h4.w;
      a1[2] += wb0 * h4.x + wb1 * h4.y + wb2 * h4.z + wb3 * h4.w;
      a2[2] += wc0 * h4.x + wc1 * h4.y + wc2 * h4.z + wc3 * h4.w;
    }
    // slice 2, k=164..191: streamed (sb 20..26)
#pragma unroll
    for (int sb = 20; sb < 27; ++sb) {
      const float4 h4 = *(const float4*)&h_s[164 + (sb - 20) * 4];
      const float4 w0 = W4[(sb * 3 + 0) * 256 + tid];
      const float4 w1 = W4[(sb * 3 + 1) * 256 + tid];
      const float4 w2 = W4[(sb * 3 + 2) * 256 + tid];
      a0[2] += w0.x * h4.x + w0.y * h4.y + w0.z * h4.z + w0.w * h4.w;
      a1[2] += w1.x * h4.x + w1.y * h4.y + w1.z * h4.z + w1.w * h4.w;
      a2[2] += w2.x * h4.x + w2.y * h4.y + w2.z * h4.z + w2.w * h4.w;
    }
    // slice 3, k=192..255: streamed (sb 27..42)
#pragma unroll
    for (int sb = 27; sb < 43; ++sb) {
      const float4 h4 = *(const float4*)&h_s[192 + (sb - 27) * 4];
      const float4 w0 = W4[(sb * 3 + 0) * 256 + tid];
      const float4 w1 = W4[(sb * 3 + 1) * 256 + tid];
      const float4 w2 = W4[(sb * 3 + 2) * 256 + tid];
      a0[3] += w0.x * h4.x + w0.y * h4.y + w0.z * h4.z + w0.w * h4.w;
      a1[3] += w1.x * h4.x + w1.y * h4.y + w1.z * h4.z + w1.w * h4.w;
      a2[3] += w2.x * h4.x + w2.y * h4.y + w2.z * h4.z + w2.w * h4.w;
    }
    // out(t-1) + tf(t) on wave 0 (reads h_s = h(t-1); identical code to R12)
    if (t > 0 && tid < 64) {
      const float h0 = h_s[tid], h1 = h_s[tid + 64], h2 = h_s[tid + 128], h3 = h_s[tid + 192];
      float p[10];
#pragma unroll
      for (int cc = 0; cc < 10; ++cc)
        p[cc] = wfs[cc * 256 + tid] * h0 + wfs[cc * 256 + tid + 64] * h1 +
                wfs[cc * 256 + tid + 128] * h2 + wfs[cc * 256 + tid + 192] * h3;
#pragma unroll
      for (int off = 32; off > 0; off >>= 1)
#pragma unroll
        for (int cc = 0; cc < 10; ++cc) p[cc] += __shfl_xor(p[cc], off);
      if (tid == 0) {
#pragma unroll
        for (int cc = 0; cc < 10; ++cc) {
          const float o = p[cc] + bf_s[cc];
          out[(b * T_ + (t - 1)) * 10 + cc] = o;
          tf_s[cc] = (fm_r > 0) ? tg_r[cc] : (o > 0.f ? 1.f : 0.f);
        }
        fm_r = force_mask[t * B_ + b];  // prefetch step t for next iteration's out
#pragma unroll
        for (int cc = 0; cc < 10; ++cc) tg_r[cc] = targets[(b * T_ + t) * 10 + cc];
      }
    }
    __syncthreads();  // partials done (thread-local), tf_s(t) ready, h_s reads done
    // ---- phase B: gate -> h(t) (thread d owns dim d; same fp order as R12) ----
    {
      float gr = gi_r, gz = gi_z, gn0 = gi_n;
#pragma unroll
      for (int cc = 0; cc < 10; ++cc) {
        const float tfv = tf_s[cc];
        gr += wtf[cc * 768 + tid] * tfv;
        gz += wtf[cc * 768 + 256 + tid] * tfv;
        gn0 += wtf[cc * 768 + 512 + tid] * tfv;
      }
      const float ghr = bhh_r + a0[0] + a0[1] + a0[2] + a0[3];
      const float ghz = bhh_z + a1[0] + a1[1] + a1[2] + a1[3];
      const float ghn = bhh_n + a2[0] + a2[1] + a2[2] + a2[3];
      const float r = 1.f / (1.f + expf(-(gr + ghr)));
      const float z = 1.f / (1.f + expf(-(gz + ghz)));
      const float n = tanhf(gn0 + r * ghn);
      h_s[tid] = (1.f - z) * n + z * h_s[tid];
    }
    __syncthreads();  // h(t) visible for next matvec
  }
  // ---- epilogue: out(T-1) ----
  if (tid < 64) {
    const float h0 = h_s[tid], h1 = h_s[tid + 64], h2 = h_s[tid + 128], h3 = h_s[tid + 192];
    float p[10];
#pragma unroll
    for (int cc = 0; cc < 10; ++cc)
      p[cc] = wfs[cc * 256 + tid] * h0 + wfs[cc * 256 + tid + 64] * h1 +
              wfs[cc * 256 + tid + 128] * h2 + wfs[cc * 256 + tid + 192] * h3;
#pragma unroll
    for (int off = 32; off > 0; off >>= 1)
#pragma unroll
      for (int cc = 0; cc < 10; ++cc) p[cc] += __shfl_xor(p[cc], off);
    if (tid == 0) {
#pragma unroll
      for (int cc = 0; cc < 10; ++cc)
        out[(b * T_ + (T_ - 1)) * 10 + cc] = p[cc] + bf_s[cc];
    }
  }
}

extern "C" void kernel_launch(void* const* d_in, const int* in_sizes, int n_in,
                              void* d_out, int out_size, void* d_ws, size_t ws_size,
                              hipStream_t stream) {
  const float* x = (const float*)d_in[0];
  const float* targets = (const float*)d_in[1];
  const int* fmask = (const int*)d_in[2];
  const float* W1 = (const float*)d_in[3];
  const float* b1 = (const float*)d_in[4];
  const float* W2 = (const float*)d_in[5];
  const float* b2 = (const float*)d_in[6];
  const float* W3 = (const float*)d_in[7];
  const float* b3 = (const float*)d_in[8];
  const float* Wih = (const float*)d_in[9];
  const float* Whh = (const float*)d_in[10];
  const float* bih = (const float*)d_in[11];
  const float* bhh = (const float*)d_in[12];
  const float* Wf = (const float*)d_in[13];
  const float* bf = (const float*)d_in[14];
  float* out = (float*)d_out;
  float* ws = (float*)d_ws;
  // workspace layout (floats), peak 29,949,952 (~114.25 MiB).
  // y2 aliases gi (y2 dead after conv3, gi written after — stream-ordered, safe).
  // Wstr aliases feats (feats dead after gid_kernel; prep2 runs after gid).
  float* WhhT = ws;                 // 196608
  float* W2t = ws + 196608;         // 147456
  float* W3t = ws + 344064;         // 147456
  float* WihT4 = ws + 491520;       // 98304
  float* feats = ws + 589824;       // 4194304
  float* gi = ws + 4784128;         // 25165824
  float* y2 = gi;                   // 8388608 (alias)
  float* Wstr = feats;              // 132096 (alias, dead feats)

  prep_kernel<<<2304, 256, 0, stream>>>(Whh, W2, W3, Wih, WhhT, W2t, W3t, WihT4);
  conv12_kernel<<<dim3(256, 32), 256, 0, stream>>>(x, W1, b1, W2t, b2, y2);
  conv3_kernel<<<dim3(256, 32), 256, 0, stream>>>(y2, W3t, b3, feats);
  gid_kernel<<<dim3(3, 1024), 256, 0, stream>>>(feats, WihT4, bih, gi);
  prep2_kernel<<<516, 256, 0, stream>>>(Whh, Wstr);
  rnn_kernel<<<32, 256, 0, stream>>>(gi, WhhT, Wstr, Wih, bhh, Wf, bf, targets, fmask, out);
}